// Round 24
// baseline (157.570 us; speedup 1.0000x reference)
//
#include <hip/hip_runtime.h>

// FactorizedSpectralConv: B=8, S1=S2=256, C=64, M1=M2=32.
// R24 = R23 structure with the pw<->XfG aliasing RACE fixed:
//   R23's k_mi<2> wrote pw (aliased over XfG) while mix-dim1 blocks in the
//   same launch still read XfG-dim1 -> absmax 6.4e-3. Fix: pw gets its own
//   region (OFF_PW2, after XfG) when ws allows (WS_FULL tier); otherwise
//   fall back to the proven-safe serial R19 sequence (aliased pw is fine
//   when idft<2> runs after all XfG readers).
//
// Lessons: R23 aliased scratch + cross-stage merge = race (check liveness
// across merged launches!); R3-5/R21 spills; R12 lane-contiguous producer
// stores; R13/14 epilogue rolled; R9/R21 no operand duplication; R17/18
// consumer reads sector-dense; R19 latency-bound = more blocks.
// MFMA mapping: k f(g2,e)=8*g2+e both operands; C/D col=lane&31,
// row=(reg&3)+8*(reg>>2)+4*(lane>>5)  [HW-verified].

namespace {

constexpr int S = 256, C = 64;

typedef _Float16 f16;
typedef _Float16 f16x2 __attribute__((ext_vector_type(2)));
typedef _Float16 f16x4 __attribute__((ext_vector_type(4)));
typedef _Float16 f16x8 __attribute__((ext_vector_type(8)));
typedef float f32x16 __attribute__((ext_vector_type(16)));
typedef unsigned int u32;

// ws layout (float offsets)
constexpr int OFF_FWDF = 0;
constexpr int OFF_INVF = 8192;
constexpr int OFF_A2   = 16384;
constexpr int OFF_YT   = 540672;    // YtG: 8388608 fl
constexpr int OFF_XF   = 8929280;   // XfG: 8388608 fl
constexpr int OFF_PW2  = 17317888;  // pw (non-aliased): 16777216 fl
constexpr size_t WS_RMW  = (size_t)(OFF_XF + 8388608) * 4;    //  69.3 MB
constexpr size_t WS_PW   = (size_t)(OFF_XF + 16777216) * 4;   // 102.8 MB (aliased pw)
constexpr size_t WS_FULL = (size_t)(OFF_PW2 + 16777216) * 4;  // 136.4 MB (own pw)

constexpr size_t XF_DB = 1048576;
constexpr size_t YT_DB = 1048576;

constexpr int P   = 4624;          // 256-col pitch
constexpr int LDS_BYTES = 8 * P;   // 36992

__device__ __host__ inline int cadr(int c) { return c * 16 + (c >> 3) * 16; }
__device__ inline int yadr(int r, int c) { return 1152 * r + c * 4 + (c >> 5) * 16; }

// ---- merged init (unchanged) ----
__global__ void k_init_all(const float* __restrict__ k0r, const float* __restrict__ k0i,
                           const float* __restrict__ k1r, const float* __restrict__ ki1,
                           float* __restrict__ ws) {
  const int bid = blockIdx.x;
  if (bid < 128) {
    int t = bid * 256 + threadIdx.x;
    f16* fwdF = (f16*)(ws + OFF_FWDF);
    f16* invF = (f16*)(ws + OFF_INVF);
    if (t < 16384) {
      int e = t & 7, lane = (t >> 3) & 63, mtkk = t >> 9;
      int mt = mtkk & 1, kk = mtkk >> 1;
      int mc = mt * 32 + (lane & 31);
      int x = kk * 16 + 8 * (lane >> 5) + e;
      int r = mc >> 1;
      float ang = (float)((r * x) & 255) * (3.14159265358979323846f / 128.0f);
      float v = (mc & 1) ? -sinf(ang) : cosf(ang);
      fwdF[t] = (f16)v;
    } else {
      int t2 = t - 16384;
      int e = t2 & 7, lane = (t2 >> 3) & 63, mtg = (t2 >> 9) & 7, kk = t2 >> 12;
      int u = mtg * 32 + (lane & 31);
      int mcv = kk * 16 + 8 * (lane >> 5) + e;
      int r = mcv >> 1;
      float wgt = (r == 0) ? 1.0f : 2.0f;
      float ang = (float)((r * u) & 255) * (3.14159265358979323846f / 128.0f);
      float v = (mcv & 1) ? -wgt * sinf(ang) : wgt * cosf(ang);
      invF[t2] = (f16)(v * (1.0f / 256.0f));
    }
    return;
  }
  const int db = bid - 128;
  const float* kr = (db < 2048) ? k0r : k1r;
  const float* ki = (db < 2048) ? k0i : ki1;
  f16* A2 = (f16*)(ws + OFF_A2) + ((db < 2048) ? 0 : 524288);
  int t = (db & 2047) * 256 + threadIdx.x;
  int e = t & 7, l = (t >> 3) & 63, kk = (t >> 9) & 7, mt = (t >> 12) & 3, r = t >> 14;
  int m = mt * 32 + (l & 31);
  int kreal = kk * 16 + 8 * (l >> 5) + e;
  int i = m >> 1, imo = m & 1, j = kreal >> 1, imi = kreal & 1;
  int src = (r * 64 + i) * 64 + j;
  float v = (imi == 0) ? ((imo == 0) ? kr[src] : ki[src])
                       : ((imo == 0) ? -ki[src] : kr[src]);
  A2[t] = (f16)v;
}

// ---- component: DFT body (512-thr, 4-slab form; dim runtime) ----
__device__ inline void dft4_body(int dim, int local, char* sm,
                                 const float* __restrict__ X,
                                 const float* __restrict__ ws,
                                 f16* __restrict__ xfg) {
  const int tid = threadIdx.x;
  const int l = tid & 63, w = tid >> 6;
  const int g2 = l >> 5, l31 = l & 31;
  const int n0 = w * 32;
  const int b = local >> 6;
  const int yt4 = (local & 63) * 4;
  const size_t bbase = (size_t)b * (S * S * C);
  const f16* fwdF = (const f16*)(ws + OFF_FWDF);

  auto gofs = [&](int u, int c) -> size_t {
    if (dim == 0)
      return bbase + (size_t)u * (S * C) + (size_t)(yt4 + (c >> 6)) * C + (c & 63);
    else
      return bbase + (size_t)(yt4 + (c >> 6)) * (S * C) + (size_t)u * C + (c & 63);
  };

  const int ug = w >> 1;
  const int c1 = (w & 1) * 128 + l;
  const int c2 = c1 + 64;

  float r1[8], r2[8];
  auto stage_load = [&](int u0) {
#pragma unroll
    for (int j = 0; j < 8; ++j) r1[j] = X[gofs(u0 + ug * 8 + j, c1)];
#pragma unroll
    for (int j = 0; j < 8; ++j) r2[j] = X[gofs(u0 + ug * 8 + j, c2)];
  };
  auto stage_write = [&](int buf) {
    f16x8 v1, v2;
#pragma unroll
    for (int j = 0; j < 8; ++j) { v1[j] = (f16)r1[j]; v2[j] = (f16)r2[j]; }
    char* base = sm + buf * (4 * P) + ug * P;
    *(f16x8*)(base + cadr(c1)) = v1;
    *(f16x8*)(base + cadr(c2)) = v2;
  };

  f32x16 acc0, acc1;
#pragma unroll
  for (int q = 0; q < 16; ++q) { acc0[q] = 0.f; acc1[q] = 0.f; }

  stage_load(0);
  stage_write(0);
  __syncthreads();

  for (int ch = 0; ch < 8; ++ch) {
    if (ch < 7) stage_load((ch + 1) * 32);
    const char* bbuf = sm + (ch & 1) * (4 * P);
#pragma unroll
    for (int ks = 0; ks < 2; ++ks) {
      const int kk = ch * 2 + ks;
      f16x8 bf = *(const f16x8*)(bbuf + (ks * 2 + g2) * P + cadr(n0 + l31));
      f16x8 a0 = *(const f16x8*)(fwdF + ((size_t)(kk * 2 + 0) * 64 + l) * 8);
      f16x8 a1 = *(const f16x8*)(fwdF + ((size_t)(kk * 2 + 1) * 64 + l) * 8);
      acc0 = __builtin_amdgcn_mfma_f32_32x32x16_f16(a0, bf, acc0, 0, 0, 0);
      acc1 = __builtin_amdgcn_mfma_f32_32x32x16_f16(a1, bf, acc1, 0, 0, 0);
    }
    if (ch < 7) {
      stage_write((ch + 1) & 1);
      __syncthreads();
    }
  }

  {
    f16* xfb = xfg + ((size_t)dim * 8 + b) * XF_DB;
    const int col = n0 + l31;
    const int yl = col >> 6, j = col & 63;
#pragma unroll
    for (int pr = 0; pr < 16; ++pr) {
      const int q = (pr & 7) >> 1, hf = pr & 1;
      const int r = 2 * g2 + 4 * q + hf + (pr >> 3) * 16;
      const int reg = 4 * q + 2 * hf;
      const float v0 = (pr < 8) ? acc0[reg] : acc1[reg];
      const float v1 = (pr < 8) ? acc0[reg + 1] : acc1[reg + 1];
      f16x2 v2 = {(f16)v0, (f16)v1};
      *(f16x2*)(xfb + (size_t)r * 32768 + (size_t)(yt4 + yl) * 128 + 2 * j) = v2;
    }
  }
}

// ---- component: mix body (512-thr; dim runtime, local in [0,256)) ----
__device__ inline void mix_body(int dim, int local, const float* __restrict__ ws,
                                const f16* __restrict__ xfg, f16* __restrict__ ytg) {
  const int tid = threadIdx.x;
  const int l = tid & 63, w = tid >> 6;
  const int g2 = l >> 5, l31 = l & 31;
  const int b = local >> 5;
  const int r = local & 31;
  const f16* A2f = (const f16*)(ws + OFF_A2) + (size_t)dim * 524288;
  const f16* xfb = xfg + ((size_t)dim * 8 + b) * XF_DB + (size_t)r * 32768;
  f16* ytb = ytg + ((size_t)dim * 8 + b) * YT_DB;
  const int y = w * 32 + l31;
  const size_t ybase = (size_t)(y >> 2) * 16384 + (size_t)(2 * r) * 256 + (y & 3);

  f16x8 bf[8];
#pragma unroll
  for (int kk = 0; kk < 8; ++kk)
    bf[kk] = *(const f16x8*)(xfb + (size_t)y * 128 + kk * 16 + 8 * g2);

#pragma unroll 1
  for (int mt = 0; mt < 4; ++mt) {
    f32x16 acc;
#pragma unroll
    for (int q = 0; q < 16; ++q) acc[q] = 0.f;
#pragma unroll
    for (int kk = 0; kk < 8; ++kk) {
      f16x8 af = *(const f16x8*)(A2f + ((size_t)((r * 4 + mt) * 8 + kk) * 64 + l) * 8);
      acc = __builtin_amdgcn_mfma_f32_32x32x16_f16(af, bf[kk], acc, 0, 0, 0);
    }
#pragma unroll
    for (int t = 0; t < 8; ++t) {
      const int reg = 2 * t;
      const int i = (t & 1) + 4 * (t >> 1) + 2 * g2 + 16 * mt;
      const size_t o = ybase + (size_t)i * 4;
      ytb[o] = (f16)acc[reg];
      ytb[o + 256] = (f16)acc[reg + 1];
    }
  }
}

// ---- component: iDFT body (u-split; MODE templated; local in [0,1024)) ----
template <int MODE>
__device__ inline void idft_body(int local, char* sm, const float* __restrict__ ws,
                                 const f16* __restrict__ ytg, float* __restrict__ out,
                                 f16* __restrict__ pw) {
  constexpr int DIM = (MODE == 0 || MODE == 2) ? 0 : 1;
  const int tid = threadIdx.x;
  const int l = tid & 63, w = tid >> 6;
  const int g2 = l >> 5, l31 = l & 31;
  const int n0 = w * 32;
  const int hh = local >> 9;
  const int loc = local & 511;
  const int b = loc >> 6;
  const int yt4 = (loc & 63) * 4;
  const size_t bbase = (size_t)b * (S * S * C);
  const f16* invF = (const f16*)(ws + OFF_INVF);
  const f16* ytb = ytg + ((size_t)DIM * 8 + b) * YT_DB + (size_t)(yt4 >> 2) * 16384;

#pragma unroll
  for (int p = 0; p < 8; ++p) {
    const int pair = p * 512 + tid;
    const int i = pair & 63, mc = pair >> 6;
    const int kk = mc >> 4, g2s = (mc >> 3) & 1, e = mc & 7;
    f16x4 v = *(const f16x4*)(ytb + (size_t)pair * 4);
    char* slab = sm + (kk * 2 + g2s) * 4608;
#pragma unroll
    for (int yl = 0; yl < 4; ++yl)
      *(f16*)(slab + cadr(yl * 64 + i) + e * 2) = v[yl];
  }
  __syncthreads();

  const int colg = n0 + l31;
  const int yl = colg >> 6, ii = colg & 63;
  f16x8 bf4[4];
#pragma unroll
  for (int kk = 0; kk < 4; ++kk)
    bf4[kk] = *(const f16x8*)(sm + (kk * 2 + g2) * 4608 + cadr(colg));

#pragma unroll 1
  for (int mt = 0; mt < 4; ++mt) {
    f32x16 a4;
#pragma unroll
    for (int q = 0; q < 16; ++q) a4[q] = 0.f;
#pragma unroll
    for (int kk = 0; kk < 4; ++kk) {
      f16x8 A = *(const f16x8*)(invF + ((size_t)(kk * 8 + hh * 4 + mt) * 64 + l) * 8);
      a4 = __builtin_amdgcn_mfma_f32_32x32x16_f16(A, bf4[kk], a4, 0, 0, 0);
    }
    const int u0 = (hh * 4 + mt) * 32;
#pragma unroll
    for (int reg = 0; reg < 16; ++reg) {
      const int u = u0 + (reg & 3) + 8 * (reg >> 2) + 4 * g2;
      size_t g = (DIM == 0)
                     ? bbase + (size_t)u * (S * C) + (size_t)(yt4 + yl) * C + ii
                     : bbase + (size_t)(yt4 + yl) * (S * C) + (size_t)u * C + ii;
      if constexpr (MODE == 0)      out[g] = a4[reg];
      else if constexpr (MODE == 1) out[g] += a4[reg];
      else if constexpr (MODE == 2) pw[g] = (f16)a4[reg];
      else                          out[g] = a4[reg] + (float)pw[g];
    }
  }
}

// ---- kernels ----
__launch_bounds__(512, 2)
__global__ void k_dft0(const float* __restrict__ X, const float* __restrict__ ws,
                       f16* __restrict__ xfg) {
  __shared__ char sm[LDS_BYTES] __attribute__((aligned(16)));
  dft4_body(0, (int)blockIdx.x, sm, X, ws, xfg);
}

// both-dims serial DFT (fallback tiers)
__launch_bounds__(512, 2)
__global__ void k_dftB(const float* __restrict__ X, const float* __restrict__ ws,
                       f16* __restrict__ xfg) {
  __shared__ char sm[LDS_BYTES] __attribute__((aligned(16)));
  dft4_body((int)blockIdx.x >> 9, (int)blockIdx.x & 511, sm, X, ws, xfg);
}

// merged: 768 = 512 dft-dim1 + 256 mix-dim0 (race-free: disjoint buffers)
__launch_bounds__(512, 2)
__global__ void k_dm(const float* __restrict__ X, const float* __restrict__ ws,
                     f16* __restrict__ xfg, f16* __restrict__ ytg) {
  __shared__ char sm[LDS_BYTES] __attribute__((aligned(16)));
  const int bid = (int)blockIdx.x;
  if (bid % 3 == 2) mix_body(0, bid / 3, ws, xfg, ytg);
  else              dft4_body(1, bid - (bid + 1) / 3, sm, X, ws, xfg);
}

// both-dims serial mix (fallback tiers)
__launch_bounds__(512, 2)
__global__ void k_mixB(const float* __restrict__ ws, const f16* __restrict__ xfg,
                       f16* __restrict__ ytg) {
  mix_body((int)blockIdx.x >> 8, (int)blockIdx.x & 255, ws, xfg, ytg);
}

// merged: 1280 = 1024 idft<MODE>-dim0 + 256 mix-dim1.
// SAFE ONLY when pw does NOT alias XfG (WS_FULL tier).
template <int MODE>
__launch_bounds__(512, 4)
__global__ void k_mi(const float* __restrict__ ws, const f16* __restrict__ xfg,
                     f16* __restrict__ ytg, float* __restrict__ out,
                     f16* __restrict__ pw) {
  __shared__ char sm[8 * 4608] __attribute__((aligned(16)));
  const int bid = (int)blockIdx.x;
  if (bid % 5 == 4) mix_body(1, bid / 5, ws, xfg, ytg);
  else              idft_body<MODE>(bid - (bid + 1) / 5, sm, ws, ytg, out, pw);
}

template <int MODE>
__launch_bounds__(512, 4)
__global__ void k_idft(const float* __restrict__ ws, const f16* __restrict__ ytg,
                       float* __restrict__ out, f16* __restrict__ pw) {
  __shared__ char sm[8 * 4608] __attribute__((aligned(16)));
  idft_body<MODE>((int)blockIdx.x, sm, ws, ytg, out, pw);
}

// ---- R15 fused fallback (tables-only ws) ----
template <int MODE>
__launch_bounds__(512, 2)
__global__ void k_dim(const float* __restrict__ X, const float* __restrict__ ws,
                      float* __restrict__ out) {
  constexpr int DIM = (MODE == 0) ? 0 : 1;
  __shared__ char sm[LDS_BYTES] __attribute__((aligned(16)));
  const int tid = threadIdx.x;
  const int l = tid & 63, w = tid >> 6;
  const int g2 = l >> 5, l31 = l & 31;
  const int n0 = w * 32;
  const int bid = (DIM == 1) ? (int)(gridDim.x - 1 - blockIdx.x) : (int)blockIdx.x;
  const int b = bid >> 6;
  const int t4 = (bid & 63) * 4;
  const size_t bbase = (size_t)b * (S * S * C);
  const f16* fwdF = (const f16*)(ws + OFF_FWDF);
  const f16* invF = (const f16*)(ws + OFF_INVF);
  const f16* A2 = (const f16*)(ws + OFF_A2) + (DIM == 0 ? 0 : 524288);
  const int colg = n0 + l31;
  const int pp = colg >> 6, jj = colg & 63;

  auto gofs = [&](int u, int c) -> size_t {
    if (DIM == 0)
      return bbase + (size_t)u * (S * C) + (size_t)(t4 + (c >> 6)) * C + (c & 63);
    else
      return bbase + (size_t)(t4 + (c >> 6)) * (S * C) + (size_t)u * C + (c & 63);
  };
  const int ug = w >> 1;
  const int c1 = (w & 1) * 128 + l;
  const int c2 = c1 + 64;
  float r1[8], r2[8];
  auto stage_load = [&](int u0) {
#pragma unroll
    for (int j = 0; j < 8; ++j) r1[j] = X[gofs(u0 + ug * 8 + j, c1)];
#pragma unroll
    for (int j = 0; j < 8; ++j) r2[j] = X[gofs(u0 + ug * 8 + j, c2)];
  };
  auto stage_write = [&](int buf) {
    f16x8 v1, v2;
#pragma unroll
    for (int j = 0; j < 8; ++j) { v1[j] = (f16)r1[j]; v2[j] = (f16)r2[j]; }
    char* base = sm + buf * (4 * P) + ug * P;
    *(f16x8*)(base + cadr(c1)) = v1;
    *(f16x8*)(base + cadr(c2)) = v2;
  };

  f32x16 acc0, acc1;
#pragma unroll
  for (int q = 0; q < 16; ++q) { acc0[q] = 0.f; acc1[q] = 0.f; }
  stage_load(0);
  stage_write(0);
  __syncthreads();
  for (int ch = 0; ch < 8; ++ch) {
    if (ch < 7) stage_load((ch + 1) * 32);
    const char* bbuf = sm + (ch & 1) * (4 * P);
#pragma unroll
    for (int ks = 0; ks < 2; ++ks) {
      const int kk = ch * 2 + ks;
      f16x8 bf = *(const f16x8*)(bbuf + (ks * 2 + g2) * P + cadr(n0 + l31));
      f16x8 a0 = *(const f16x8*)(fwdF + ((size_t)(kk * 2 + 0) * 64 + l) * 8);
      f16x8 a1 = *(const f16x8*)(fwdF + ((size_t)(kk * 2 + 1) * 64 + l) * 8);
      acc0 = __builtin_amdgcn_mfma_f32_32x32x16_f16(a0, bf, acc0, 0, 0, 0);
      acc1 = __builtin_amdgcn_mfma_f32_32x32x16_f16(a1, bf, acc1, 0, 0, 0);
    }
    if (ch < 7) { stage_write((ch + 1) & 1); __syncthreads(); }
  }
  __syncthreads();
  {
    const int col = n0 + l31;
    const int p = col >> 6, j = col & 63;
    const int kk = j >> 3, g2p = (j >> 2) & 1, js = j & 3;
#pragma unroll
    for (int pr = 0; pr < 16; ++pr) {
      const int q = (pr & 7) >> 1, hf = pr & 1;
      const int r = 2 * g2 + 4 * q + hf + (pr >> 3) * 16;
      const int reg = 4 * q + 2 * hf;
      const float v0 = (pr < 8) ? acc0[reg] : acc1[reg];
      const float v1 = (pr < 8) ? acc0[reg + 1] : acc1[reg + 1];
      f16x2 v2 = {(f16)v0, (f16)v1};
      const int W = (r * 16 + kk * 2 + g2p) * 4 + p;
      *(f16x2*)(sm + W * 16 + (W >> 3) * 16 + js * 4) = v2;
    }
  }
  __syncthreads();
  {
    const int colsel = l31 & 3;
#pragma unroll 1
    for (int rq = 0; rq < 4; ++rq) {
      const int r = w * 4 + rq;
      f16x8 bfr[8];
#pragma unroll
      for (int kk = 0; kk < 8; ++kk) {
        const int W = (r * 16 + kk * 2 + g2) * 4 + colsel;
        bfr[kk] = *(const f16x8*)(sm + W * 16 + (W >> 3) * 16);
      }
#pragma unroll 1
      for (int mt = 0; mt < 4; ++mt) {
        f32x16 acc;
#pragma unroll
        for (int q = 0; q < 16; ++q) acc[q] = 0.f;
#pragma unroll
        for (int kk = 0; kk < 8; ++kk) {
          f16x8 af = *(const f16x8*)(A2 + ((size_t)((r * 4 + mt) * 8 + kk) * 64 + l) * 8);
          acc = __builtin_amdgcn_mfma_f32_32x32x16_f16(af, bfr[kk], acc, 0, 0, 0);
        }
        if (l31 < 4) {
#pragma unroll
          for (int t2 = 0; t2 < 8; ++t2) {
            int reg = t2 * 2;
            int rowin = (reg & 3) + 8 * (reg >> 2) + 4 * g2;
            int i = (mt * 32 + rowin) >> 1;
            f16x2 v2 = {(f16)acc[reg], (f16)acc[reg + 1]};
            *(f16x2*)(sm + yadr(r, l31 * 64 + i)) = v2;
          }
        }
      }
    }
  }
  __syncthreads();
  f16x8 bf4[4];
  {
    const int cb = colg * 4 + (colg >> 5) * 16;
#pragma unroll
    for (int kk = 0; kk < 4; ++kk) {
      union { f16x8 h; u32 u[4]; } bb;
      const int r0 = 8 * kk + 4 * g2;
#pragma unroll
      for (int s = 0; s < 4; ++s)
        bb.u[s] = *(const u32*)(sm + 1152 * (r0 + s) + cb);
      bf4[kk] = bb.h;
    }
  }
#pragma unroll 1
  for (int h = 0; h < 2; ++h) {
#pragma unroll 1
    for (int mt = 0; mt < 4; ++mt) {
      f32x16 a4;
#pragma unroll
      for (int q = 0; q < 16; ++q) a4[q] = 0.f;
#pragma unroll
      for (int kk = 0; kk < 4; ++kk) {
        f16x8 A = *(const f16x8*)(invF + ((size_t)(kk * 8 + h * 4 + mt) * 64 + l) * 8);
        a4 = __builtin_amdgcn_mfma_f32_32x32x16_f16(A, bf4[kk], a4, 0, 0, 0);
      }
      const int u0 = (h * 4 + mt) * 32;
#pragma unroll
      for (int reg = 0; reg < 16; ++reg) {
        const int u = u0 + (reg & 3) + 8 * (reg >> 2) + 4 * g2;
        size_t g = (DIM == 0)
                       ? bbase + (size_t)u * (S * C) + (size_t)(t4 + pp) * C + jj
                       : bbase + (size_t)(t4 + pp) * (S * C) + (size_t)u * C + jj;
        if constexpr (MODE == 0) out[g] = a4[reg];
        else                     out[g] += a4[reg];
      }
    }
  }
}

}  // namespace

extern "C" void kernel_launch(void* const* d_in, const int* in_sizes, int n_in,
                              void* d_out, int out_size, void* d_ws, size_t ws_size,
                              hipStream_t stream) {
  (void)in_sizes; (void)n_in; (void)out_size;
  const float* X   = (const float*)d_in[0];
  const float* k0r = (const float*)d_in[1];
  const float* k0i = (const float*)d_in[2];
  const float* k1r = (const float*)d_in[3];
  const float* k1i = (const float*)d_in[4];
  float* out = (float*)d_out;
  float* ws  = (float*)d_ws;
  f16* ytg = (f16*)(ws + OFF_YT);
  f16* xfg = (f16*)(ws + OFF_XF);

  k_init_all<<<4224, 256, 0, stream>>>(k0r, k0i, k1r, k1i, ws);
  if (ws_size >= WS_FULL) {
    // merged pipeline; pw has its OWN region (no XfG alias -> race-free)
    f16* pw = (f16*)(ws + OFF_PW2);
    k_dft0<<<512, 512, 0, stream>>>(X, ws, xfg);               // dft dim0
    k_dm<<<768, 512, 0, stream>>>(X, ws, xfg, ytg);            // dft d1 + mix d0
    k_mi<2><<<1280, 512, 0, stream>>>(ws, xfg, ytg, out, pw);  // idft<2> d0 + mix d1
    k_idft<3><<<1024, 512, 0, stream>>>(ws, ytg, out, pw);     // idft<3> d1
  } else if (ws_size >= WS_PW) {
    // proven serial R19 sequence; aliased pw is safe here (XfG dead by then)
    f16* pw = (f16*)(ws + OFF_XF);
    k_dftB<<<1024, 512, 0, stream>>>(X, ws, xfg);
    k_mixB<<<512, 512, 0, stream>>>(ws, xfg, ytg);
    k_idft<2><<<1024, 512, 0, stream>>>(ws, ytg, out, pw);
    k_idft<3><<<1024, 512, 0, stream>>>(ws, ytg, out, pw);
  } else if (ws_size >= WS_RMW) {
    k_dftB<<<1024, 512, 0, stream>>>(X, ws, xfg);
    k_mixB<<<512, 512, 0, stream>>>(ws, xfg, ytg);
    k_idft<0><<<1024, 512, 0, stream>>>(ws, ytg, out, nullptr);
    k_idft<1><<<1024, 512, 0, stream>>>(ws, ytg, out, nullptr);
  } else {
    k_dim<0><<<512, 512, 0, stream>>>(X, ws, out);
    k_dim<1><<<512, 512, 0, stream>>>(X, ws, out);
  }
}

// Round 25
// 137.456 us; speedup vs baseline: 1.1463x; 1.1463x over previous
//
#include <hip/hip_runtime.h>

// FactorizedSpectralConv: B=8, S1=S2=256, C=64, M1=M2=32.
// R25 = exact revert to R20 (best measured: 138.5us).
// De-fused 3-stage: k_dft (NP=2, 2048 blk) -> k_mix (512 blk) ->
// k_idft u-split (1024 blk, pw f16 tier). R21-R24 probes (occupancy caps,
// mt-split, cross-stage merges) all regressed or raced; co-residency lever
// is dead. This is the surviving optimum (~1.5x above pure-traffic floor,
// latency-structure plateau, no saturated pipe).
//
// Lessons ledger: R3-5/R21 spills; R12 producer stores lane-contiguous;
// R13/14 epilogue rolled+simple; R9/R21 no operand duplication across
// blocks; R17/18 consumer reads sector-dense; R19 latency-bound = more
// blocks (when regs allow); R16/R23/R24 co-residency merging: dead end.
// MFMA mapping: logical k f(g2,e)=8*g2+e on BOTH operands; C/D layout
// col=lane&31, row=(reg&3)+8*(reg>>2)+4*(lane>>5)  [HW-verified].

namespace {

constexpr int S = 256, C = 64;

typedef _Float16 f16;
typedef _Float16 f16x2 __attribute__((ext_vector_type(2)));
typedef _Float16 f16x4 __attribute__((ext_vector_type(4)));
typedef _Float16 f16x8 __attribute__((ext_vector_type(8)));
typedef float f32x16 __attribute__((ext_vector_type(16)));
typedef unsigned int u32;

// ws layout (float offsets)
constexpr int OFF_FWDF = 0;        // fwd A-frag table: 16384 f16
constexpr int OFF_INVF = 8192;     // inv A-frag table: 16384 f16
constexpr int OFF_A2   = 16384;    // mix A-frag tables: 2 dims x 524288 f16
constexpr int OFF_YT   = 540672;   // YtG: 8388608 fl
constexpr int OFF_XF   = 8929280;  // XfG: 8388608 fl
constexpr size_t WS_RMW = (size_t)(OFF_XF + 8388608) * 4;
constexpr size_t WS_PW  = (size_t)(OFF_XF + 16777216) * 4;

// per-(dim,b) strides in f16 elements
constexpr size_t XF_DB = 1048576;  // 32 r * 256 y * 128 kreal
constexpr size_t YT_DB = 1048576;  // 64 yq * 64 mc * 64 i * 4 yl

// LDS geometry: 16B/col + 16B pad per 8 cols
constexpr int P   = 4624;          // 256-col pitch (fallback k_dim)
constexpr int P2  = 2304;          // 128-col pitch (k_dft, NP=2)
constexpr int LDS_BYTES = 8 * P;   // 36992 (fallback)

__device__ __host__ inline int cadr(int c) { return c * 16 + (c >> 3) * 16; }
__device__ inline int yadr(int r, int c) { return 1152 * r + c * 4 + (c >> 5) * 16; }

// ---- merged init: DFT/iDFT A-frag tables + both mix A2 tables ----
__global__ void k_init_all(const float* __restrict__ k0r, const float* __restrict__ k0i,
                           const float* __restrict__ k1r, const float* __restrict__ ki1,
                           float* __restrict__ ws) {
  const int bid = blockIdx.x;
  if (bid < 128) {
    int t = bid * 256 + threadIdx.x;
    f16* fwdF = (f16*)(ws + OFF_FWDF);
    f16* invF = (f16*)(ws + OFF_INVF);
    if (t < 16384) {
      int e = t & 7, lane = (t >> 3) & 63, mtkk = t >> 9;
      int mt = mtkk & 1, kk = mtkk >> 1;
      int mc = mt * 32 + (lane & 31);
      int x = kk * 16 + 8 * (lane >> 5) + e;
      int r = mc >> 1;
      float ang = (float)((r * x) & 255) * (3.14159265358979323846f / 128.0f);
      float v = (mc & 1) ? -sinf(ang) : cosf(ang);
      fwdF[t] = (f16)v;
    } else {
      int t2 = t - 16384;
      int e = t2 & 7, lane = (t2 >> 3) & 63, mtg = (t2 >> 9) & 7, kk = t2 >> 12;
      int u = mtg * 32 + (lane & 31);
      int mcv = kk * 16 + 8 * (lane >> 5) + e;
      int r = mcv >> 1;
      float wgt = (r == 0) ? 1.0f : 2.0f;
      float ang = (float)((r * u) & 255) * (3.14159265358979323846f / 128.0f);
      float v = (mcv & 1) ? -wgt * sinf(ang) : wgt * cosf(ang);
      invF[t2] = (f16)(v * (1.0f / 256.0f));
    }
    return;
  }
  const int db = bid - 128;
  const float* kr = (db < 2048) ? k0r : k1r;
  const float* ki = (db < 2048) ? k0i : ki1;
  f16* A2 = (f16*)(ws + OFF_A2) + ((db < 2048) ? 0 : 524288);
  int t = (db & 2047) * 256 + threadIdx.x;
  int e = t & 7, l = (t >> 3) & 63, kk = (t >> 9) & 7, mt = (t >> 12) & 3, r = t >> 14;
  int m = mt * 32 + (l & 31);
  int kreal = kk * 16 + 8 * (l >> 5) + e;
  int i = m >> 1, imo = m & 1, j = kreal >> 1, imi = kreal & 1;
  int src = (r * 64 + i) * 64 + j;
  float v = (imi == 0) ? ((imo == 0) ? kr[src] : ki[src])
                       : ((imo == 0) ? -ki[src] : kr[src]);
  A2[t] = (f16)v;
}

// ---- stage A: DFT (both dims), NP=2: 256 threads, 2048 blocks ----
__launch_bounds__(256, 4)
__global__ void k_dft(const float* __restrict__ X, const float* __restrict__ ws,
                      f16* __restrict__ xfg) {
  __shared__ char sm[8 * P2] __attribute__((aligned(16)));   // 18432 B
  const int tid = threadIdx.x;
  const int l = tid & 63, w = tid >> 6;    // 4 waves
  const int g2 = l >> 5, l31 = l & 31;
  const int n0 = w * 32;                   // [0,128)
  const int dim = (int)blockIdx.x >> 10;
  const int local = (int)blockIdx.x & 1023;
  const int b = local >> 7;
  const int yt2 = (local & 127) * 2;       // 2 slabs per block
  const size_t bbase = (size_t)b * (S * S * C);
  const f16* fwdF = (const f16*)(ws + OFF_FWDF);

  auto gofs = [&](int u, int c) -> size_t {
    if (dim == 0)
      return bbase + (size_t)u * (S * C) + (size_t)(yt2 + (c >> 6)) * C + (c & 63);
    else
      return bbase + (size_t)(yt2 + (c >> 6)) * (S * C) + (size_t)u * C + (c & 63);
  };

  const int c1 = l;
  const int c2 = l + 64;

  float r1[8], r2[8];
  auto stage_load = [&](int u0) {
#pragma unroll
    for (int j = 0; j < 8; ++j) r1[j] = X[gofs(u0 + w * 8 + j, c1)];
#pragma unroll
    for (int j = 0; j < 8; ++j) r2[j] = X[gofs(u0 + w * 8 + j, c2)];
  };
  auto stage_write = [&](int buf) {
    f16x8 v1, v2;
#pragma unroll
    for (int j = 0; j < 8; ++j) { v1[j] = (f16)r1[j]; v2[j] = (f16)r2[j]; }
    char* base = sm + buf * (4 * P2) + w * P2;
    *(f16x8*)(base + cadr(c1)) = v1;
    *(f16x8*)(base + cadr(c2)) = v2;
  };

  f32x16 acc0, acc1;
#pragma unroll
  for (int q = 0; q < 16; ++q) { acc0[q] = 0.f; acc1[q] = 0.f; }

  stage_load(0);
  stage_write(0);
  __syncthreads();

  for (int ch = 0; ch < 8; ++ch) {
    if (ch < 7) stage_load((ch + 1) * 32);
    const char* bbuf = sm + (ch & 1) * (4 * P2);
#pragma unroll
    for (int ks = 0; ks < 2; ++ks) {
      const int kk = ch * 2 + ks;
      f16x8 bf = *(const f16x8*)(bbuf + (ks * 2 + g2) * P2 + cadr(n0 + l31));
      f16x8 a0 = *(const f16x8*)(fwdF + ((size_t)(kk * 2 + 0) * 64 + l) * 8);
      f16x8 a1 = *(const f16x8*)(fwdF + ((size_t)(kk * 2 + 1) * 64 + l) * 8);
      acc0 = __builtin_amdgcn_mfma_f32_32x32x16_f16(a0, bf, acc0, 0, 0, 0);
      acc1 = __builtin_amdgcn_mfma_f32_32x32x16_f16(a1, bf, acc1, 0, 0, 0);
    }
    if (ch < 7) {
      stage_write((ch + 1) & 1);
      __syncthreads();
    }
  }

  // C -> XfG[dim][b][r][y][kreal] (dense 128B per half-wave per pr)
  {
    f16* xfb = xfg + ((size_t)dim * 8 + b) * XF_DB;
    const int col = n0 + l31;
    const int yl = col >> 6, j = col & 63;
#pragma unroll
    for (int pr = 0; pr < 16; ++pr) {
      const int q = (pr & 7) >> 1, hf = pr & 1;
      const int r = 2 * g2 + 4 * q + hf + (pr >> 3) * 16;
      const int reg = 4 * q + 2 * hf;
      const float v0 = (pr < 8) ? acc0[reg] : acc1[reg];
      const float v1 = (pr < 8) ? acc0[reg + 1] : acc1[reg + 1];
      f16x2 v2 = {(f16)v0, (f16)v1};
      *(f16x2*)(xfb + (size_t)r * 32768 + (size_t)(yt2 + yl) * 128 + 2 * j) = v2;
    }
  }
}

// ---- stage B: per-(dim,b,mode) complex mix: XfG -> YtG (yq-major) ----
__launch_bounds__(512, 2)
__global__ void k_mix(const float* __restrict__ ws, const f16* __restrict__ xfg,
                      f16* __restrict__ ytg) {
  const int tid = threadIdx.x;
  const int l = tid & 63, w = tid >> 6;
  const int g2 = l >> 5, l31 = l & 31;
  const int dim = (int)blockIdx.x >> 8;
  const int b = ((int)blockIdx.x >> 5) & 7;
  const int r = (int)blockIdx.x & 31;
  const f16* A2f = (const f16*)(ws + OFF_A2) + (size_t)dim * 524288;
  const f16* xfb = xfg + ((size_t)dim * 8 + b) * XF_DB + (size_t)r * 32768;
  f16* ytb = ytg + ((size_t)dim * 8 + b) * YT_DB;
  const int y = w * 32 + l31;
  const size_t ybase = (size_t)(y >> 2) * 16384 + (size_t)(2 * r) * 256 + (y & 3);

  f16x8 bf[8];
#pragma unroll
  for (int kk = 0; kk < 8; ++kk)
    bf[kk] = *(const f16x8*)(xfb + (size_t)y * 128 + kk * 16 + 8 * g2);

#pragma unroll 1
  for (int mt = 0; mt < 4; ++mt) {
    f32x16 acc;
#pragma unroll
    for (int q = 0; q < 16; ++q) acc[q] = 0.f;
#pragma unroll
    for (int kk = 0; kk < 8; ++kk) {
      f16x8 af = *(const f16x8*)(A2f + ((size_t)((r * 4 + mt) * 8 + kk) * 64 + l) * 8);
      acc = __builtin_amdgcn_mfma_f32_32x32x16_f16(af, bf[kk], acc, 0, 0, 0);
    }
    // C rows m=2i+imo -> YtG[yq][mc=2r+imo][i][yl]
#pragma unroll
    for (int t = 0; t < 8; ++t) {
      const int reg = 2 * t;
      const int i = (t & 1) + 4 * (t >> 1) + 2 * g2 + 16 * mt;
      const size_t o = ybase + (size_t)i * 4;
      ytb[o] = (f16)acc[reg];            // Re (mc = 2r)
      ytb[o + 256] = (f16)acc[reg + 1];  // Im (mc = 2r+1)
    }
  }
}

// ---- stage C: per-dim iDFT (u-split): YtG -> LDS -> out/pw ----
// grid 1024: hh = bid>>9 picks u-half; 4 blocks/CU.
template <int MODE>
__launch_bounds__(512, 4)
__global__ void k_idft(const float* __restrict__ ws, const f16* __restrict__ ytg,
                       float* __restrict__ out, f16* __restrict__ pw) {
  constexpr int DIM = (MODE == 0 || MODE == 2) ? 0 : 1;
  __shared__ char sm[8 * 4608] __attribute__((aligned(16)));   // 36864 B
  const int tid = threadIdx.x;
  const int l = tid & 63, w = tid >> 6;
  const int g2 = l >> 5, l31 = l & 31;
  const int n0 = w * 32;
  const int hh = (int)blockIdx.x >> 9;
  const int local = (int)blockIdx.x & 511;
  const int b = local >> 6;
  const int yt4 = (local & 63) * 4;
  const size_t bbase = (size_t)b * (S * S * C);
  const f16* invF = (const f16*)(ws + OFF_INVF);
  const f16* ytb = ytg + ((size_t)DIM * 8 + b) * YT_DB + (size_t)(yt4 >> 2) * 16384;

  // stage Yt tile (32KB contiguous) -> LDS [kk][g2][col=(yl*64+i)][e]
#pragma unroll
  for (int p = 0; p < 8; ++p) {
    const int pair = p * 512 + tid;        // 4096 (mc,i) pairs; read = pair*8B
    const int i = pair & 63, mc = pair >> 6;
    const int kk = mc >> 4, g2s = (mc >> 3) & 1, e = mc & 7;
    f16x4 v = *(const f16x4*)(ytb + (size_t)pair * 4);
    char* slab = sm + (kk * 2 + g2s) * 4608;
#pragma unroll
    for (int yl = 0; yl < 4; ++yl)
      *(f16*)(slab + cadr(yl * 64 + i) + e * 2) = v[yl];
  }
  __syncthreads();

  const int colg = n0 + l31;
  const int yl = colg >> 6, ii = colg & 63;
  f16x8 bf4[4];
#pragma unroll
  for (int kk = 0; kk < 4; ++kk)
    bf4[kk] = *(const f16x8*)(sm + (kk * 2 + g2) * 4608 + cadr(colg));

#pragma unroll 1
  for (int mt = 0; mt < 4; ++mt) {
    f32x16 a4;
#pragma unroll
    for (int q = 0; q < 16; ++q) a4[q] = 0.f;
#pragma unroll
    for (int kk = 0; kk < 4; ++kk) {
      f16x8 A = *(const f16x8*)(invF + ((size_t)(kk * 8 + hh * 4 + mt) * 64 + l) * 8);
      a4 = __builtin_amdgcn_mfma_f32_32x32x16_f16(A, bf4[kk], a4, 0, 0, 0);
    }
    const int u0 = (hh * 4 + mt) * 32;
#pragma unroll
    for (int reg = 0; reg < 16; ++reg) {
      const int u = u0 + (reg & 3) + 8 * (reg >> 2) + 4 * g2;
      size_t g = (DIM == 0)
                     ? bbase + (size_t)u * (S * C) + (size_t)(yt4 + yl) * C + ii
                     : bbase + (size_t)(yt4 + yl) * (S * C) + (size_t)u * C + ii;
      if constexpr (MODE == 0)      out[g] = a4[reg];
      else if constexpr (MODE == 1) out[g] += a4[reg];
      else if constexpr (MODE == 2) pw[g] = (f16)a4[reg];
      else                          out[g] = a4[reg] + (float)pw[g];
    }
  }
}

// ---- R15 fused fallback (unchanged, tables-only ws) ----
template <int MODE>
__launch_bounds__(512, 2)
__global__ void k_dim(const float* __restrict__ X, const float* __restrict__ ws,
                      float* __restrict__ out) {
  constexpr int DIM = (MODE == 0) ? 0 : 1;
  __shared__ char sm[LDS_BYTES] __attribute__((aligned(16)));
  const int tid = threadIdx.x;
  const int l = tid & 63, w = tid >> 6;
  const int g2 = l >> 5, l31 = l & 31;
  const int n0 = w * 32;
  const int bid = (DIM == 1) ? (int)(gridDim.x - 1 - blockIdx.x) : (int)blockIdx.x;
  const int b = bid >> 6;
  const int t4 = (bid & 63) * 4;
  const size_t bbase = (size_t)b * (S * S * C);
  const f16* fwdF = (const f16*)(ws + OFF_FWDF);
  const f16* invF = (const f16*)(ws + OFF_INVF);
  const f16* A2 = (const f16*)(ws + OFF_A2) + (DIM == 0 ? 0 : 524288);
  const int colg = n0 + l31;
  const int pp = colg >> 6, jj = colg & 63;

  auto gofs = [&](int u, int c) -> size_t {
    if (DIM == 0)
      return bbase + (size_t)u * (S * C) + (size_t)(t4 + (c >> 6)) * C + (c & 63);
    else
      return bbase + (size_t)(t4 + (c >> 6)) * (S * C) + (size_t)u * C + (c & 63);
  };
  const int ug = w >> 1;
  const int c1 = (w & 1) * 128 + l;
  const int c2 = c1 + 64;
  float r1[8], r2[8];
  auto stage_load = [&](int u0) {
#pragma unroll
    for (int j = 0; j < 8; ++j) r1[j] = X[gofs(u0 + ug * 8 + j, c1)];
#pragma unroll
    for (int j = 0; j < 8; ++j) r2[j] = X[gofs(u0 + ug * 8 + j, c2)];
  };
  auto stage_write = [&](int buf) {
    f16x8 v1, v2;
#pragma unroll
    for (int j = 0; j < 8; ++j) { v1[j] = (f16)r1[j]; v2[j] = (f16)r2[j]; }
    char* base = sm + buf * (4 * P) + ug * P;
    *(f16x8*)(base + cadr(c1)) = v1;
    *(f16x8*)(base + cadr(c2)) = v2;
  };

  f32x16 acc0, acc1;
#pragma unroll
  for (int q = 0; q < 16; ++q) { acc0[q] = 0.f; acc1[q] = 0.f; }
  stage_load(0);
  stage_write(0);
  __syncthreads();
  for (int ch = 0; ch < 8; ++ch) {
    if (ch < 7) stage_load((ch + 1) * 32);
    const char* bbuf = sm + (ch & 1) * (4 * P);
#pragma unroll
    for (int ks = 0; ks < 2; ++ks) {
      const int kk = ch * 2 + ks;
      f16x8 bf = *(const f16x8*)(bbuf + (ks * 2 + g2) * P + cadr(n0 + l31));
      f16x8 a0 = *(const f16x8*)(fwdF + ((size_t)(kk * 2 + 0) * 64 + l) * 8);
      f16x8 a1 = *(const f16x8*)(fwdF + ((size_t)(kk * 2 + 1) * 64 + l) * 8);
      acc0 = __builtin_amdgcn_mfma_f32_32x32x16_f16(a0, bf, acc0, 0, 0, 0);
      acc1 = __builtin_amdgcn_mfma_f32_32x32x16_f16(a1, bf, acc1, 0, 0, 0);
    }
    if (ch < 7) { stage_write((ch + 1) & 1); __syncthreads(); }
  }
  __syncthreads();
  {
    const int col = n0 + l31;
    const int p = col >> 6, j = col & 63;
    const int kk = j >> 3, g2p = (j >> 2) & 1, js = j & 3;
#pragma unroll
    for (int pr = 0; pr < 16; ++pr) {
      const int q = (pr & 7) >> 1, hf = pr & 1;
      const int r = 2 * g2 + 4 * q + hf + (pr >> 3) * 16;
      const int reg = 4 * q + 2 * hf;
      const float v0 = (pr < 8) ? acc0[reg] : acc1[reg];
      const float v1 = (pr < 8) ? acc0[reg + 1] : acc1[reg + 1];
      f16x2 v2 = {(f16)v0, (f16)v1};
      const int W = (r * 16 + kk * 2 + g2p) * 4 + p;
      *(f16x2*)(sm + W * 16 + (W >> 3) * 16 + js * 4) = v2;
    }
  }
  __syncthreads();
  {
    const int colsel = l31 & 3;
#pragma unroll 1
    for (int rq = 0; rq < 4; ++rq) {
      const int r = w * 4 + rq;
      f16x8 bfr[8];
#pragma unroll
      for (int kk = 0; kk < 8; ++kk) {
        const int W = (r * 16 + kk * 2 + g2) * 4 + colsel;
        bfr[kk] = *(const f16x8*)(sm + W * 16 + (W >> 3) * 16);
      }
#pragma unroll 1
      for (int mt = 0; mt < 4; ++mt) {
        f32x16 acc;
#pragma unroll
        for (int q = 0; q < 16; ++q) acc[q] = 0.f;
#pragma unroll
        for (int kk = 0; kk < 8; ++kk) {
          f16x8 af = *(const f16x8*)(A2 + ((size_t)((r * 4 + mt) * 8 + kk) * 64 + l) * 8);
          acc = __builtin_amdgcn_mfma_f32_32x32x16_f16(af, bfr[kk], acc, 0, 0, 0);
        }
        if (l31 < 4) {
#pragma unroll
          for (int t2 = 0; t2 < 8; ++t2) {
            int reg = t2 * 2;
            int rowin = (reg & 3) + 8 * (reg >> 2) + 4 * g2;
            int i = (mt * 32 + rowin) >> 1;
            f16x2 v2 = {(f16)acc[reg], (f16)acc[reg + 1]};
            *(f16x2*)(sm + yadr(r, l31 * 64 + i)) = v2;
          }
        }
      }
    }
  }
  __syncthreads();
  f16x8 bf4[4];
  {
    const int cb = colg * 4 + (colg >> 5) * 16;
#pragma unroll
    for (int kk = 0; kk < 4; ++kk) {
      union { f16x8 h; u32 u[4]; } bb;
      const int r0 = 8 * kk + 4 * g2;
#pragma unroll
      for (int s = 0; s < 4; ++s)
        bb.u[s] = *(const u32*)(sm + 1152 * (r0 + s) + cb);
      bf4[kk] = bb.h;
    }
  }
#pragma unroll 1
  for (int h = 0; h < 2; ++h) {
#pragma unroll 1
    for (int mt = 0; mt < 4; ++mt) {
      f32x16 a4;
#pragma unroll
      for (int q = 0; q < 16; ++q) a4[q] = 0.f;
#pragma unroll
      for (int kk = 0; kk < 4; ++kk) {
        f16x8 A = *(const f16x8*)(invF + ((size_t)(kk * 8 + h * 4 + mt) * 64 + l) * 8);
        a4 = __builtin_amdgcn_mfma_f32_32x32x16_f16(A, bf4[kk], a4, 0, 0, 0);
      }
      const int u0 = (h * 4 + mt) * 32;
#pragma unroll
      for (int reg = 0; reg < 16; ++reg) {
        const int u = u0 + (reg & 3) + 8 * (reg >> 2) + 4 * g2;
        size_t g = (DIM == 0)
                       ? bbase + (size_t)u * (S * C) + (size_t)(t4 + pp) * C + jj
                       : bbase + (size_t)(t4 + pp) * (S * C) + (size_t)u * C + jj;
        if constexpr (MODE == 0) out[g] = a4[reg];
        else                     out[g] += a4[reg];
      }
    }
  }
}

}  // namespace

extern "C" void kernel_launch(void* const* d_in, const int* in_sizes, int n_in,
                              void* d_out, int out_size, void* d_ws, size_t ws_size,
                              hipStream_t stream) {
  (void)in_sizes; (void)n_in; (void)out_size;
  const float* X   = (const float*)d_in[0];
  const float* k0r = (const float*)d_in[1];
  const float* k0i = (const float*)d_in[2];
  const float* k1r = (const float*)d_in[3];
  const float* k1i = (const float*)d_in[4];
  float* out = (float*)d_out;
  float* ws  = (float*)d_ws;
  f16* ytg = (f16*)(ws + OFF_YT);
  f16* xfg = (f16*)(ws + OFF_XF);
  f16* pw  = (f16*)(ws + OFF_XF);   // pw aliases dead XfG (safe: serial order)

  k_init_all<<<4224, 256, 0, stream>>>(k0r, k0i, k1r, k1i, ws);
  if (ws_size >= WS_RMW) {
    k_dft<<<2048, 256, 0, stream>>>(X, ws, xfg);       // both dims -> XfG (NP=2)
    k_mix<<<512, 512, 0, stream>>>(ws, xfg, ytg);      // both dims -> YtG
    if (ws_size >= WS_PW) {
      k_idft<2><<<1024, 512, 0, stream>>>(ws, ytg, out, pw);   // dim0 -> pw f16
      k_idft<3><<<1024, 512, 0, stream>>>(ws, ytg, out, pw);   // dim1 + pw -> out
    } else {
      k_idft<0><<<1024, 512, 0, stream>>>(ws, ytg, out, nullptr);
      k_idft<1><<<1024, 512, 0, stream>>>(ws, ytg, out, nullptr);
    }
  } else {
    k_dim<0><<<512, 512, 0, stream>>>(X, ws, out);
    k_dim<1><<<512, 512, 0, stream>>>(X, ws, out);
  }
}